// Round 3
// baseline (151.194 us; speedup 1.0000x reference)
//
#include <hip/hip_runtime.h>

// RankingLoss: B=16384 rows, D=1024 fp32, C=14 int32 labels -> scalar fp32.
//
// R3: latency-bound fix — ONE memory round per wave, 4x wave count.
// Block (4 waves, 256 thr) handles 4 output rows (data rows r..r+4).
// Wave w owns K-quarter w: lane loads exactly one float4 from each of the
// 10 row streams (5 rows x {zi,zt}) -> 10 independent loads, single vmcnt
// wait, 30 FMAs, one 6-step shuffle reduce, LDS combine across waves.
// Margins via wave-0 ballots (binary labels: equal <=> xor-sum==0).
// Phase 2: one block reduces 4096 block partials deterministically.

constexpr int D   = 1024;
constexpr int C   = 14;
constexpr int RPB = 4;   // output rows per block
constexpr int WPB = 4;   // waves per block

__device__ __forceinline__ float dot4(const float4 x, const float4 y) {
    return x.x * y.x + x.y * y.y + x.z * y.z + x.w * y.w;
}

__global__ __launch_bounds__(256) void rank_phase1(
    const float* __restrict__ zi, const float* __restrict__ zt,
    const int* __restrict__ labels, float* __restrict__ partial, int B)
{
    const int wave = threadIdx.x >> 6;
    const int lane = threadIdx.x & 63;
    const int r0   = blockIdx.x * RPB;
    const int M    = B - 1;                 // B is a power of two
    const int idx  = wave * 64 + lane;      // float4 index within the row

    // 10 independent coalesced loads (compiler: SGPR base + shared voffset).
    float4 a[RPB + 1], b[RPB + 1];
    #pragma unroll
    for (int k = 0; k <= RPB; ++k) {
        const int r = (r0 + k) & M;
        a[k] = ((const float4*)(zi + (size_t)r * D))[idx];
        b[k] = ((const float4*)(zt + (size_t)r * D))[idx];
    }

    float p[RPB], ii[RPB], it[RPB];
    #pragma unroll
    for (int k = 0; k < RPB; ++k) {
        p [k] = dot4(a[k],     b[k]);   // paired   dot(zi[k],  zt[k])
        ii[k] = dot4(a[k + 1], b[k]);   // imp_img  dot(zi[k+1],zt[k])
        it[k] = dot4(b[k + 1], a[k]);   // imp_txt  dot(zt[k+1],zi[k])
    }

    // Margins on wave 0 only: lane = 16*k + c covers class c of row r0+k.
    unsigned long long bx = 0, bo = 0;
    if (wave == 0) {
        const int kk = lane >> 4;
        const int c  = lane & 15;
        int lx = 0, lo = 0;
        if (c < C) {
            const int ra = (r0 + kk)     & M;
            const int rb = (r0 + kk + 1) & M;
            const int li = labels[(size_t)ra * C + c];
            const int lj = labels[(size_t)rb * C + c];
            lx = li ^ lj;
            lo = li | lj;
        }
        bx = __ballot(lx != 0);
        bo = __ballot(lo != 0);
    }

    // Wave-reduce the 12 partials (independent chains pipeline).
    #pragma unroll
    for (int off = 32; off > 0; off >>= 1) {
        #pragma unroll
        for (int k = 0; k < RPB; ++k) {
            p [k] += __shfl_down(p [k], off, 64);
            ii[k] += __shfl_down(ii[k], off, 64);
            it[k] += __shfl_down(it[k], off, 64);
        }
    }

    __shared__ float sm[WPB][12];
    if (lane == 0) {
        #pragma unroll
        for (int k = 0; k < RPB; ++k) {
            sm[wave][k * 3 + 0] = p [k];
            sm[wave][k * 3 + 1] = ii[k];
            sm[wave][k * 3 + 2] = it[k];
        }
    }
    __syncthreads();

    if (threadIdx.x == 0) {  // thread 0 is in wave 0: holds bx/bo
        float local = 0.f;
        #pragma unroll
        for (int k = 0; k < RPB; ++k) {
            float ps = 0.f, is = 0.f, ts = 0.f;
            #pragma unroll
            for (int w = 0; w < WPB; ++w) {
                ps += sm[w][k * 3 + 0];
                is += sm[w][k * 3 + 1];
                ts += sm[w][k * 3 + 2];
            }
            const float dv = (float)__popcll((bx >> (16 * k)) & 0x3FFFull);
            const float nv = (float)__popcll((bo >> (16 * k)) & 0x3FFFull);
            const float m  = (dv == 0.f) ? 0.f : fmaxf(0.5f, dv / nv);
            local += fmaxf(is - ps + m, 0.f) + fmaxf(ts - ps + m, 0.f);
        }
        partial[blockIdx.x] = local;
    }
}

__global__ __launch_bounds__(256) void rank_phase2(
    const float* __restrict__ partial, float* __restrict__ out,
    int npart, float invB)
{
    float s = 0.f;
    for (int i = threadIdx.x; i < npart; i += 256) s += partial[i];
    #pragma unroll
    for (int off = 32; off > 0; off >>= 1) s += __shfl_down(s, off, 64);
    __shared__ float sm[4];
    if ((threadIdx.x & 63) == 0) sm[threadIdx.x >> 6] = s;
    __syncthreads();
    if (threadIdx.x == 0)
        out[0] = (sm[0] + sm[1] + sm[2] + sm[3]) * invB;
}

extern "C" void kernel_launch(void* const* d_in, const int* in_sizes, int n_in,
                              void* d_out, int out_size, void* d_ws, size_t ws_size,
                              hipStream_t stream) {
    const float* zi     = (const float*)d_in[0];
    const float* zt     = (const float*)d_in[1];
    const int*   labels = (const int*)d_in[2];
    float*       out    = (float*)d_out;
    float*       ws     = (float*)d_ws;

    const int B      = in_sizes[0] / D;  // 16384
    const int blocks = B / RPB;          // 4096

    rank_phase1<<<blocks, 256, 0, stream>>>(zi, zt, labels, ws, B);
    rank_phase2<<<1, 256, 0, stream>>>(ws, out, blocks, 1.0f / (float)B);
}